// Round 8
// baseline (6570.302 us; speedup 1.0000x reference)
//
#include <hip/hip_runtime.h>
#include <hip/hip_bf16.h>
#include <math.h>

#define BATCH 16
#define C_IN 8
#define C_MID 64
#define C_OUT 128
#define LEN 512
#define TSTEPS 50
#define HZN 8
#define TL 16    // l-tile per block (rnn_step and encoders)

// ---------------------------------------------------------------------------
// Tiled encoder conv1d (k=3, same-pad) + activation, fp64.
// Block: 256 threads, covers (b, all Cout, TL=16 l).
//   lt = tid&3 -> 4 l-subtiles of 4; og = tid>>2 (0..63) -> OPT=Cout/64 o's.
// LDS: input tile [Ci][TL+2] fp64 (Ci=64 -> 9.2 KB).
// ACT: 0=none, 1=relu, 2=tanh
// ---------------------------------------------------------------------------
template <typename Tin, int Ci, int Cout, int ACT>
__global__ __launch_bounds__(256)
void enc_conv(const Tin* __restrict__ x, const float* __restrict__ w,
              const float* __restrict__ bias, double* __restrict__ y) {
    constexpr int OPT = Cout / 64;   // o's per thread (1 or 2)
    const int l0 = blockIdx.x * TL;
    const int b  = blockIdx.y;
    const int tid = threadIdx.x;
    const int lt = tid & 3;
    const int o0 = (tid >> 2) * OPT;

    __shared__ double xs[Ci][TL + 2];
    for (int k = tid; k < Ci * (TL + 2); k += 256) {
        const int i = k / (TL + 2);
        const int j = k - i * (TL + 2);
        const int gl = l0 + j - 1;
        const bool ok = (gl >= 0) && (gl < LEN);
        xs[i][j] = ok ? (double)x[((size_t)b * Ci + i) * LEN + gl] : 0.0;
    }
    __syncthreads();

    double acc[OPT][4];
    #pragma unroll
    for (int oo = 0; oo < OPT; ++oo) {
        const double bv = (double)bias[o0 + oo];
        #pragma unroll
        for (int ll = 0; ll < 4; ++ll) acc[oo][ll] = bv;
    }

    const int lb = lt * 4;
    #pragma unroll 4
    for (int i = 0; i < Ci; ++i) {
        double xv[6];
        #pragma unroll
        for (int c = 0; c < 6; ++c) xv[c] = xs[i][lb + c];
        #pragma unroll
        for (int oo = 0; oo < OPT; ++oo) {
            const float* wp = &w[((o0 + oo) * Ci + i) * 3];
            const double w0 = (double)wp[0], w1 = (double)wp[1], w2 = (double)wp[2];
            #pragma unroll
            for (int ll = 0; ll < 4; ++ll)
                acc[oo][ll] += w0 * xv[ll] + w1 * xv[ll + 1] + w2 * xv[ll + 2];
        }
    }

    #pragma unroll
    for (int oo = 0; oo < OPT; ++oo) {
        #pragma unroll
        for (int ll = 0; ll < 4; ++ll) {
            double v = acc[oo][ll];
            if (ACT == 1) v = v > 0.0 ? v : 0.0;
            else if (ACT == 2) v = tanh(v);
            y[((size_t)b * Cout + o0 + oo) * LEN + l0 + lb + ll] = v;
        }
    }
}

__global__ void zero_f64(double* __restrict__ p, int n) {
    int i = blockIdx.x * 256 + threadIdx.x;
    if (i < n) p[i] = 0.0;
}

// ---------------------------------------------------------------------------
// One coRNN step, fp64, LDS-tiled + register-blocked 4o x 4l per thread.
// Block: 128 threads covering (b, all 128 o, TL=16 l).
//   lt = tid&3 (4 l-subtiles of 4), o0 = (tid>>2)*4 (4 o's/thread)
// LDS: hy/hz tiles [128][TL+2] fp64 (36.9 KB) -> 4 blocks/CU, 8 waves/CU.
// Per channel i: 12 LDS doubles + 24 weight floats -> 96 fp64 FMAs.
// ---------------------------------------------------------------------------
__global__ __launch_bounds__(128, 2)
void rnn_step(const double* __restrict__ hy, const double* __restrict__ hz,
              const double* __restrict__ om, const double* __restrict__ al,
              const double* __restrict__ xd,
              const float* __restrict__ wy, const float* __restrict__ by,
              const float* __restrict__ wz, const float* __restrict__ bz,
              double* __restrict__ hyo, double* __restrict__ hzo,
              float* __restrict__ yseq, int t) {
    const int l0 = blockIdx.x * TL;
    const int b  = blockIdx.y;
    const int tid = threadIdx.x;
    const int lt = tid & 3;
    const int o0 = (tid >> 2) * 4;
    const size_t base = (size_t)b * C_OUT * LEN;

    __shared__ double hys[C_OUT][TL + 2];
    __shared__ double hzs[C_OUT][TL + 2];
    for (int k = tid; k < C_OUT * (TL + 2); k += 128) {
        const int i = k / (TL + 2);
        const int j = k - i * (TL + 2);
        const int gl = l0 + j - 1;
        const bool ok = (gl >= 0) && (gl < LEN);
        const size_t gi = base + (size_t)i * LEN + gl;
        hys[i][j] = ok ? hy[gi] : 0.0;
        hzs[i][j] = ok ? hz[gi] : 0.0;
    }
    __syncthreads();

    double ay[4][4], az[4][4];
    #pragma unroll
    for (int oo = 0; oo < 4; ++oo) {
        const double vy = (double)by[o0 + oo];
        const double vz = (double)bz[o0 + oo];
        #pragma unroll
        for (int ll = 0; ll < 4; ++ll) { ay[oo][ll] = vy; az[oo][ll] = vz; }
    }

    const int lb = lt * 4;
    #pragma unroll 2
    for (int i = 0; i < C_OUT; ++i) {
        double hv[6], zv[6];
        #pragma unroll
        for (int c = 0; c < 6; ++c) { hv[c] = hys[i][lb + c]; zv[c] = hzs[i][lb + c]; }
        #pragma unroll
        for (int oo = 0; oo < 4; ++oo) {
            const float* wyp = &wy[((o0 + oo) * C_OUT + i) * 3];
            const float* wzp = &wz[((o0 + oo) * C_OUT + i) * 3];
            const double w0 = (double)wyp[0], w1 = (double)wyp[1], w2 = (double)wyp[2];
            const double v0 = (double)wzp[0], v1 = (double)wzp[1], v2 = (double)wzp[2];
            #pragma unroll
            for (int ll = 0; ll < 4; ++ll) {
                ay[oo][ll] += w0 * hv[ll] + w1 * hv[ll + 1] + w2 * hv[ll + 2];
                az[oo][ll] += v0 * zv[ll] + v1 * zv[ll + 1] + v2 * zv[ll + 2];
            }
        }
    }

    #pragma unroll
    for (int oo = 0; oo < 4; ++oo) {
        const int o = o0 + oo;
        #pragma unroll
        for (int ll = 0; ll < 4; ++ll) {
            const int l = l0 + lb + ll;
            const size_t idx = base + (size_t)o * LEN + l;
            const double hyv = hys[o][lb + ll + 1];
            const double hzv = hzs[o][lb + ll + 1];
            const double pre = tanh(ay[oo][ll] + az[oo][ll] + xd[idx]);
            const double hzn = hzv + 0.5 * (pre - om[idx] * hyv - al[idx] * hzv);
            const double hyn = hyv + 0.5 * hzn;
            hzo[idx] = hzn;
            hyo[idx] = hyn;
            yseq[((size_t)(b * TSTEPS + t) * C_OUT + o) * LEN + l] = (float)hyn;
        }
    }
}

// ---------------------------------------------------------------------------
// Readout: feat = mean_L(hy_T); 3-layer MLP (fp64); fp32 predictions.
// ---------------------------------------------------------------------------
__global__ void readout(const double* __restrict__ hyT,
                        const float* __restrict__ fw1, const float* __restrict__ fb1,
                        const float* __restrict__ fw2, const float* __restrict__ fb2,
                        const float* __restrict__ fw3, const float* __restrict__ fb3,
                        float* __restrict__ pred) {
    const int b = blockIdx.x;
    const int t = threadIdx.x;  // 128 threads
    __shared__ double feat[C_OUT];
    __shared__ double h1[64];
    __shared__ double h2[32];

    {
        double s = 0.0;
        const double* p = &hyT[((size_t)b * C_OUT + t) * LEN];
        for (int l = 0; l < LEN; ++l) s += p[l];
        feat[t] = s * (1.0 / LEN);
    }
    __syncthreads();
    if (t < 64) {
        double s = (double)fb1[t];
        for (int i = 0; i < C_OUT; ++i) s += (double)fw1[t * C_OUT + i] * feat[i];
        h1[t] = s > 0.0 ? s : 0.0;
    }
    __syncthreads();
    if (t < 32) {
        double s = (double)fb2[t];
        for (int i = 0; i < 64; ++i) s += (double)fw2[t * 64 + i] * h1[i];
        h2[t] = s > 0.0 ? s : 0.0;
    }
    __syncthreads();
    if (t < HZN) {
        double s = (double)fb3[t];
        for (int i = 0; i < 32; ++i) s += (double)fw3[t * 32 + i] * h2[i];
        pred[b * HZN + t] = (float)s;
    }
}

// ---------------------------------------------------------------------------
extern "C" void kernel_launch(void* const* d_in, const int* in_sizes, int n_in,
                              void* d_out, int out_size, void* d_ws, size_t ws_size,
                              hipStream_t stream) {
    const float* x   = (const float*)d_in[0];
    const float* ow1 = (const float*)d_in[1];  const float* ob1 = (const float*)d_in[2];
    const float* ow2 = (const float*)d_in[3];  const float* ob2 = (const float*)d_in[4];
    const float* ow3 = (const float*)d_in[5];  const float* ob3 = (const float*)d_in[6];
    const float* aw1 = (const float*)d_in[7];  const float* ab1 = (const float*)d_in[8];
    const float* aw2 = (const float*)d_in[9];  const float* ab2 = (const float*)d_in[10];
    const float* aw3 = (const float*)d_in[11]; const float* ab3 = (const float*)d_in[12];
    const float* hw1 = (const float*)d_in[13]; const float* hb1 = (const float*)d_in[14];
    const float* hw2 = (const float*)d_in[15]; const float* hb2 = (const float*)d_in[16];
    const float* hw3 = (const float*)d_in[17]; const float* hb3 = (const float*)d_in[18];
    const float* hw4 = (const float*)d_in[19]; const float* hb4 = (const float*)d_in[20];
    const float* cwy = (const float*)d_in[21]; const float* cby = (const float*)d_in[22];
    const float* cwz = (const float*)d_in[23]; const float* cbz = (const float*)d_in[24];
    const float* cwx = (const float*)d_in[25]; const float* cbx = (const float*)d_in[26];
    const float* fw1 = (const float*)d_in[27]; const float* fb1 = (const float*)d_in[28];
    const float* fw2 = (const float*)d_in[29]; const float* fb2 = (const float*)d_in[30];
    const float* fw3 = (const float*)d_in[31]; const float* fb3 = (const float*)d_in[32];

    float* out  = (float*)d_out;
    float* pred = out;                    // (B, HZN) fp32
    float* yseq = out + BATCH * HZN;      // (B, T, C_OUT, LEN) fp32

    // workspace: 7 fp64 state buffers (8 MB each = 56 MB total).
    // Encoder temps alias hyB/hzB (unused until the recurrence starts).
    const size_t SZ = (size_t)BATCH * C_OUT * LEN;  // 1,048,576 elements
    double* ws  = (double*)d_ws;
    double* om  = ws + 0 * SZ;
    double* al  = ws + 1 * SZ;
    double* xd  = ws + 2 * SZ;
    double* hyA = ws + 3 * SZ;
    double* hzA = ws + 4 * SZ;
    double* hyB = ws + 5 * SZ;
    double* hzB = ws + 6 * SZ;
    double* t1  = hyB;  // (B, C_MID, L) = 4 MB, fits in 8 MB
    double* t2  = hzB;

    dim3 egrid(LEN / TL, BATCH);   // (32, 16)
    const int go = (BATCH * C_OUT * LEN + 255) / 256;  // 4096 blocks (zero fill)

    // omega encoder
    enc_conv<float,  C_IN,  C_MID, 1><<<egrid, 256, 0, stream>>>(x,  ow1, ob1, t1);
    enc_conv<double, C_MID, C_MID, 1><<<egrid, 256, 0, stream>>>(t1, ow2, ob2, t2);
    enc_conv<double, C_MID, C_OUT, 1><<<egrid, 256, 0, stream>>>(t2, ow3, ob3, om);
    // alpha encoder
    enc_conv<float,  C_IN,  C_MID, 1><<<egrid, 256, 0, stream>>>(x,  aw1, ab1, t1);
    enc_conv<double, C_MID, C_MID, 1><<<egrid, 256, 0, stream>>>(t1, aw2, ab2, t2);
    enc_conv<double, C_MID, C_OUT, 1><<<egrid, 256, 0, stream>>>(t2, aw3, ab3, al);
    // hy encoder
    enc_conv<float,  C_IN,  C_MID, 1><<<egrid, 256, 0, stream>>>(x,  hw1, hb1, t1);
    enc_conv<double, C_MID, C_MID, 1><<<egrid, 256, 0, stream>>>(t1, hw2, hb2, t2);
    enc_conv<double, C_MID, C_MID, 1><<<egrid, 256, 0, stream>>>(t2, hw3, hb3, t1);
    enc_conv<double, C_MID, C_OUT, 2><<<egrid, 256, 0, stream>>>(t1, hw4, hb4, hyA);
    // x drive (no activation)
    enc_conv<float,  C_IN,  C_OUT, 0><<<egrid, 256, 0, stream>>>(x, cwx, cbx, xd);
    // hz0 = 0
    zero_f64<<<go, 256, 0, stream>>>(hzA, (int)SZ);

    // recurrence (note: step 0 overwrites hyB/hzB, which held encoder temps)
    double* hy_cur = hyA; double* hz_cur = hzA;
    double* hy_nxt = hyB; double* hz_nxt = hzB;
    dim3 sgrid(LEN / TL, BATCH);
    for (int t = 0; t < TSTEPS; ++t) {
        rnn_step<<<sgrid, 128, 0, stream>>>(hy_cur, hz_cur, om, al, xd,
                                            cwy, cby, cwz, cbz,
                                            hy_nxt, hz_nxt, yseq, t);
        double* sy = hy_cur; hy_cur = hy_nxt; hy_nxt = sy;
        double* sz = hz_cur; hz_cur = hz_nxt; hz_nxt = sz;
    }

    // readout on final hy
    readout<<<BATCH, C_OUT, 0, stream>>>(hy_cur, fw1, fb1, fw2, fb2, fw3, fb3, pred);
}

// Round 9
// 2941.431 us; speedup vs baseline: 2.2337x; 2.2337x over previous
//
#include <hip/hip_runtime.h>
#include <hip/hip_bf16.h>
#include <math.h>

#define BATCH 16
#define C_IN 8
#define C_MID 64
#define C_OUT 128
#define LEN 512
#define TSTEPS 50
#define HZN 8
#define TL 16    // l-tile per block (rnn_step and encoders)

// ---------------------------------------------------------------------------
// Tiled encoder conv1d (k=3, same-pad) + activation, fp32.
// Block: 256 threads, covers (b, all Cout, TL=16 l).
//   lt = tid&3 -> 4 l-subtiles of 4; o0 = (tid>>2)*OPT, OPT=Cout/64.
// LDS: input tile [Ci][TL+2] fp32 (Ci=64 -> 4.6 KB).
// ACT: 0=none, 1=relu, 2=tanh
// ---------------------------------------------------------------------------
template <int Ci, int Cout, int ACT>
__global__ __launch_bounds__(256)
void enc_conv(const float* __restrict__ x, const float* __restrict__ w,
              const float* __restrict__ bias, float* __restrict__ y) {
    constexpr int OPT = Cout / 64;   // o's per thread (1 or 2)
    const int l0 = blockIdx.x * TL;
    const int b  = blockIdx.y;
    const int tid = threadIdx.x;
    const int lt = tid & 3;
    const int o0 = (tid >> 2) * OPT;

    __shared__ float xs[Ci][TL + 2];
    for (int k = tid; k < Ci * (TL + 2); k += 256) {
        const int i = k / (TL + 2);
        const int j = k - i * (TL + 2);
        const int gl = l0 + j - 1;
        const bool ok = (gl >= 0) && (gl < LEN);
        xs[i][j] = ok ? x[((size_t)b * Ci + i) * LEN + gl] : 0.f;
    }
    __syncthreads();

    float acc[OPT][4];
    #pragma unroll
    for (int oo = 0; oo < OPT; ++oo) {
        const float bv = bias[o0 + oo];
        #pragma unroll
        for (int ll = 0; ll < 4; ++ll) acc[oo][ll] = bv;
    }

    const int lb = lt * 4;
    #pragma unroll 4
    for (int i = 0; i < Ci; ++i) {
        float xv[6];
        #pragma unroll
        for (int c = 0; c < 6; ++c) xv[c] = xs[i][lb + c];
        #pragma unroll
        for (int oo = 0; oo < OPT; ++oo) {
            const float* wp = &w[((o0 + oo) * Ci + i) * 3];
            const float w0 = wp[0], w1 = wp[1], w2 = wp[2];
            #pragma unroll
            for (int ll = 0; ll < 4; ++ll)
                acc[oo][ll] += w0 * xv[ll] + w1 * xv[ll + 1] + w2 * xv[ll + 2];
        }
    }

    #pragma unroll
    for (int oo = 0; oo < OPT; ++oo) {
        #pragma unroll
        for (int ll = 0; ll < 4; ++ll) {
            float v = acc[oo][ll];
            if (ACT == 1) v = v > 0.f ? v : 0.f;
            else if (ACT == 2) v = tanhf(v);
            y[((size_t)b * Cout + o0 + oo) * LEN + l0 + lb + ll] = v;
        }
    }
}

__global__ void zero_f32(float* __restrict__ p, int n) {
    int i = blockIdx.x * 256 + threadIdx.x;
    if (i < n) p[i] = 0.f;
}

// ---------------------------------------------------------------------------
// One coRNN step, fp32, LDS-tiled + register-blocked 2o x 4l per thread.
// Block: 256 threads covering (b, all 128 o, TL=16 l).  (round-6 structure;
// 512 blocks x 256 thr = 2 blocks/CU = 8 waves/CU — do NOT reduce threads,
// round-8 showed 128-thr blocks halve occupancy to 1 wave/SIMD and regress.)
// LDS: hy/hz tiles [128][TL+2] fp32 (18.4 KB).
// ---------------------------------------------------------------------------
__global__ __launch_bounds__(256, 2)
void rnn_step(const float* __restrict__ hy, const float* __restrict__ hz,
              const float* __restrict__ om, const float* __restrict__ al,
              const float* __restrict__ xd,
              const float* __restrict__ wy, const float* __restrict__ by,
              const float* __restrict__ wz, const float* __restrict__ bz,
              float* __restrict__ hyo, float* __restrict__ hzo,
              float* __restrict__ yseq, int t) {
    const int l0 = blockIdx.x * TL;
    const int b  = blockIdx.y;
    const int tid = threadIdx.x;
    const int lt = tid & 3;
    const int o0 = (tid >> 2) * 2;
    const size_t base = (size_t)b * C_OUT * LEN;

    __shared__ float hys[C_OUT][TL + 2];
    __shared__ float hzs[C_OUT][TL + 2];
    for (int k = tid; k < C_OUT * (TL + 2); k += 256) {
        const int i = k / (TL + 2);
        const int j = k - i * (TL + 2);
        const int gl = l0 + j - 1;
        const bool ok = (gl >= 0) && (gl < LEN);
        const size_t gi = base + (size_t)i * LEN + gl;
        hys[i][j] = ok ? hy[gi] : 0.f;
        hzs[i][j] = ok ? hz[gi] : 0.f;
    }
    __syncthreads();

    float ay[2][4], az[2][4];
    #pragma unroll
    for (int oo = 0; oo < 2; ++oo) {
        const float vy = by[o0 + oo];
        const float vz = bz[o0 + oo];
        #pragma unroll
        for (int ll = 0; ll < 4; ++ll) { ay[oo][ll] = vy; az[oo][ll] = vz; }
    }

    const int lb = lt * 4;
    #pragma unroll 4
    for (int i = 0; i < C_OUT; ++i) {
        float hv[6], zv[6];
        #pragma unroll
        for (int c = 0; c < 6; ++c) { hv[c] = hys[i][lb + c]; zv[c] = hzs[i][lb + c]; }
        #pragma unroll
        for (int oo = 0; oo < 2; ++oo) {
            const float* wyp = &wy[((o0 + oo) * C_OUT + i) * 3];
            const float* wzp = &wz[((o0 + oo) * C_OUT + i) * 3];
            const float w0 = wyp[0], w1 = wyp[1], w2 = wyp[2];
            const float v0 = wzp[0], v1 = wzp[1], v2 = wzp[2];
            #pragma unroll
            for (int ll = 0; ll < 4; ++ll) {
                ay[oo][ll] += w0 * hv[ll] + w1 * hv[ll + 1] + w2 * hv[ll + 2];
                az[oo][ll] += v0 * zv[ll] + v1 * zv[ll + 1] + v2 * zv[ll + 2];
            }
        }
    }

    #pragma unroll
    for (int oo = 0; oo < 2; ++oo) {
        const int o = o0 + oo;
        #pragma unroll
        for (int ll = 0; ll < 4; ++ll) {
            const int l = l0 + lb + ll;
            const size_t idx = base + (size_t)o * LEN + l;
            const float hyv = hys[o][lb + ll + 1];
            const float hzv = hzs[o][lb + ll + 1];
            const float pre = tanhf(ay[oo][ll] + az[oo][ll] + xd[idx]);
            const float hzn = hzv + 0.5f * (pre - om[idx] * hyv - al[idx] * hzv);
            const float hyn = hyv + 0.5f * hzn;
            hzo[idx] = hzn;
            hyo[idx] = hyn;
            yseq[((size_t)(b * TSTEPS + t) * C_OUT + o) * LEN + l] = hyn;
        }
    }
}

// ---------------------------------------------------------------------------
// Readout: feat = mean_L(hy_T); 3-layer MLP (fp64 accum over fp32 data).
// ---------------------------------------------------------------------------
__global__ void readout(const float* __restrict__ hyT,
                        const float* __restrict__ fw1, const float* __restrict__ fb1,
                        const float* __restrict__ fw2, const float* __restrict__ fb2,
                        const float* __restrict__ fw3, const float* __restrict__ fb3,
                        float* __restrict__ pred) {
    const int b = blockIdx.x;
    const int t = threadIdx.x;  // 128 threads
    __shared__ double feat[C_OUT];
    __shared__ double h1[64];
    __shared__ double h2[32];

    {
        double s = 0.0;
        const float* p = &hyT[((size_t)b * C_OUT + t) * LEN];
        for (int l = 0; l < LEN; ++l) s += (double)p[l];
        feat[t] = s * (1.0 / LEN);
    }
    __syncthreads();
    if (t < 64) {
        double s = (double)fb1[t];
        for (int i = 0; i < C_OUT; ++i) s += (double)fw1[t * C_OUT + i] * feat[i];
        h1[t] = s > 0.0 ? s : 0.0;
    }
    __syncthreads();
    if (t < 32) {
        double s = (double)fb2[t];
        for (int i = 0; i < 64; ++i) s += (double)fw2[t * 64 + i] * h1[i];
        h2[t] = s > 0.0 ? s : 0.0;
    }
    __syncthreads();
    if (t < HZN) {
        double s = (double)fb3[t];
        for (int i = 0; i < 32; ++i) s += (double)fw3[t * 32 + i] * h2[i];
        pred[b * HZN + t] = (float)s;
    }
}

// ---------------------------------------------------------------------------
extern "C" void kernel_launch(void* const* d_in, const int* in_sizes, int n_in,
                              void* d_out, int out_size, void* d_ws, size_t ws_size,
                              hipStream_t stream) {
    const float* x   = (const float*)d_in[0];
    const float* ow1 = (const float*)d_in[1];  const float* ob1 = (const float*)d_in[2];
    const float* ow2 = (const float*)d_in[3];  const float* ob2 = (const float*)d_in[4];
    const float* ow3 = (const float*)d_in[5];  const float* ob3 = (const float*)d_in[6];
    const float* aw1 = (const float*)d_in[7];  const float* ab1 = (const float*)d_in[8];
    const float* aw2 = (const float*)d_in[9];  const float* ab2 = (const float*)d_in[10];
    const float* aw3 = (const float*)d_in[11]; const float* ab3 = (const float*)d_in[12];
    const float* hw1 = (const float*)d_in[13]; const float* hb1 = (const float*)d_in[14];
    const float* hw2 = (const float*)d_in[15]; const float* hb2 = (const float*)d_in[16];
    const float* hw3 = (const float*)d_in[17]; const float* hb3 = (const float*)d_in[18];
    const float* hw4 = (const float*)d_in[19]; const float* hb4 = (const float*)d_in[20];
    const float* cwy = (const float*)d_in[21]; const float* cby = (const float*)d_in[22];
    const float* cwz = (const float*)d_in[23]; const float* cbz = (const float*)d_in[24];
    const float* cwx = (const float*)d_in[25]; const float* cbx = (const float*)d_in[26];
    const float* fw1 = (const float*)d_in[27]; const float* fb1 = (const float*)d_in[28];
    const float* fw2 = (const float*)d_in[29]; const float* fb2 = (const float*)d_in[30];
    const float* fw3 = (const float*)d_in[31]; const float* fb3 = (const float*)d_in[32];

    float* out  = (float*)d_out;
    float* pred = out;                    // (B, HZN) fp32
    float* yseq = out + BATCH * HZN;      // (B, T, C_OUT, LEN) fp32

    // workspace: 7 fp32 state buffers (4 MB each = 28 MB total).
    // Encoder temps alias hyB/hzB (dead once the recurrence starts).
    const size_t SZ = (size_t)BATCH * C_OUT * LEN;  // 1,048,576 elements
    float* ws  = (float*)d_ws;
    float* om  = ws + 0 * SZ;
    float* al  = ws + 1 * SZ;
    float* xd  = ws + 2 * SZ;
    float* hyA = ws + 3 * SZ;
    float* hzA = ws + 4 * SZ;
    float* hyB = ws + 5 * SZ;
    float* hzB = ws + 6 * SZ;
    float* t1  = hyB;  // (B, C_MID, L) = 2 MB, fits in 4 MB
    float* t2  = hzB;

    dim3 egrid(LEN / TL, BATCH);   // (32, 16)
    const int go = (BATCH * C_OUT * LEN + 255) / 256;  // 4096 blocks (zero fill)

    // omega encoder
    enc_conv<C_IN,  C_MID, 1><<<egrid, 256, 0, stream>>>(x,  ow1, ob1, t1);
    enc_conv<C_MID, C_MID, 1><<<egrid, 256, 0, stream>>>(t1, ow2, ob2, t2);
    enc_conv<C_MID, C_OUT, 1><<<egrid, 256, 0, stream>>>(t2, ow3, ob3, om);
    // alpha encoder
    enc_conv<C_IN,  C_MID, 1><<<egrid, 256, 0, stream>>>(x,  aw1, ab1, t1);
    enc_conv<C_MID, C_MID, 1><<<egrid, 256, 0, stream>>>(t1, aw2, ab2, t2);
    enc_conv<C_MID, C_OUT, 1><<<egrid, 256, 0, stream>>>(t2, aw3, ab3, al);
    // hy encoder
    enc_conv<C_IN,  C_MID, 1><<<egrid, 256, 0, stream>>>(x,  hw1, hb1, t1);
    enc_conv<C_MID, C_MID, 1><<<egrid, 256, 0, stream>>>(t1, hw2, hb2, t2);
    enc_conv<C_MID, C_MID, 1><<<egrid, 256, 0, stream>>>(t2, hw3, hb3, t1);
    enc_conv<C_MID, C_OUT, 2><<<egrid, 256, 0, stream>>>(t1, hw4, hb4, hyA);
    // x drive (no activation)
    enc_conv<C_IN,  C_OUT, 0><<<egrid, 256, 0, stream>>>(x, cwx, cbx, xd);
    // hz0 = 0
    zero_f32<<<go, 256, 0, stream>>>(hzA, (int)SZ);

    // recurrence (step 0 overwrites hyB/hzB, which held encoder temps)
    float* hy_cur = hyA; float* hz_cur = hzA;
    float* hy_nxt = hyB; float* hz_nxt = hzB;
    dim3 sgrid(LEN / TL, BATCH);
    for (int t = 0; t < TSTEPS; ++t) {
        rnn_step<<<sgrid, 256, 0, stream>>>(hy_cur, hz_cur, om, al, xd,
                                            cwy, cby, cwz, cbz,
                                            hy_nxt, hz_nxt, yseq, t);
        float* sy = hy_cur; hy_cur = hy_nxt; hy_nxt = sy;
        float* sz = hz_cur; hz_cur = hz_nxt; hz_nxt = sz;
    }

    // readout on final hy
    readout<<<BATCH, C_OUT, 0, stream>>>(hy_cur, fw1, fb1, fw2, fb2, fw3, fb3, pred);
}